// Round 2
// baseline (276.290 us; speedup 1.0000x reference)
//
#include <hip/hip_runtime.h>

// GMMNet: B=4,S=8,C=3,H=W=384,K=5. Pointwise per pixel; scan over S carries
// per-pixel state (pi[5], mu[15], rinv[5]=1/sigma) in registers.
//
// Round 10: R9 FAILED on a transcription bug (gamma MLP layer-1 read
// uninitialized h[i] instead of gin[i]) -- NOT the occupancy change.
// Fixed here; the R9 occupancy theory is unchanged and now actually tested:
//
// R8's CSV VGPR_Count=56 is granule-of-4 units -> ~224 actual VGPRs
// (per-thread live state alone is ~100 regs at the mu-MLP peak, so raw 56
// is impossible). 224 regs cap residency at 2 waves/SIMD -- BELOW the 4.5
// waves/SIMD the 2304x128 grid supplies. Measured OccupancyPercent 29%
// (~2.35 w/SIMD) confirms; VALUBusy 65% is the latency exposed by running
// half-occupied. Liveness says the pressure peak (mu-MLP phase 2:
// h[15]+muN[15] v2f + x/xn/rho/piN) is ~100-110 regs, so a 128-reg cap is
// feasible without spilling. __launch_bounds__(128, 4) (min 4 waves/EU ->
// VGPR<=128). Predict VALUBusy -> ~85%, dur 134 -> ~100 us.
// Tripwire: WRITE_SIZE jump == scratch spill -> retreat to (128, 3).
//
// Retained from R8: ONE contiguous d_ws weight buffer (tiny staging kernel),
// consumption-order layout, dense s_load clustering off a single base.
// Opaque scalar per-step offset retained (blocks loop-invariant weight
// hoisting into VGPRs - R2's 188-VGPR lesson).

namespace {

constexpr int Kk = 5;
constexpr int Cc = 3;
constexpr int CKc = 15;   // C*K
constexpr int Bb = 4;
constexpr int Ss = 8;
constexpr int HWc = 384 * 384;
constexpr int HW2 = HWc / 2;          // pixel-pairs per image
constexpr int BLOCK = 128;

// Contiguous weight layout (float offsets), consumption order.
constexpr int OPB1 = 0;     // pi_b1   5
constexpr int OPW1 = 5;     // pi_w1   5x10 = 50
constexpr int OPB2 = 55;    // pi_b2   5
constexpr int OPW2 = 60;    // pi_w2   5x5  = 25
constexpr int OMB1 = 85;    // mu_b1   15
constexpr int OMW1 = 100;   // mu_w1   15x23 = 345
constexpr int OMB2 = 445;   // mu_b2   15
constexpr int OMW2 = 460;   // mu_w2   15x15 = 225
constexpr int OSB1 = 685;   // sg_b1   5
constexpr int OSW1 = 690;   // sg_w1   5x23 = 115
constexpr int OSB2 = 805;   // sg_b2   5
constexpr int OSW2 = 810;   // sg_w2   5x5  = 25
constexpr int OGB1 = 835;   // ga_b1   5
constexpr int OGW1 = 840;   // ga_w1   5x5  = 25
constexpr int OGW2 = 865;   // ga_w2   5
constexpr int OGB2 = 870;   // ga_b2   1
constexpr int WTOT = 871;   // 3484 B

typedef float v2f __attribute__((ext_vector_type(2)));

__device__ __forceinline__ float rcpf(float x) { return __builtin_amdgcn_rcpf(x); }
__device__ __forceinline__ float ex2(float x) { return __builtin_amdgcn_exp2f(x); }

__device__ __forceinline__ v2f vsplat(float w) { v2f r = {w, w}; return r; }
__device__ __forceinline__ v2f vfma(v2f a, v2f b, v2f c) { return __builtin_elementwise_fma(a, b, c); }
__device__ __forceinline__ v2f wfma(float w, v2f x, v2f c) { return vfma(vsplat(w), x, c); }
__device__ __forceinline__ v2f vexp2(v2f v) { v2f r; r.x = ex2(v.x); r.y = ex2(v.y); return r; }
__device__ __forceinline__ v2f vrcp(v2f v) { v2f r; r.x = rcpf(v.x); r.y = rcpf(v.y); return r; }
__device__ __forceinline__ v2f vmax(v2f a, v2f b) { return __builtin_elementwise_max(a, b); }
__device__ __forceinline__ v2f vrelu(v2f a) { return vmax(a, vsplat(0.0f)); }
constexpr float LOG2E = 1.4426950408889634f;
__device__ __forceinline__ v2f vsigm(v2f a) { return vrcp(vsplat(1.0f) + vexp2(vsplat(-LOG2E) * a)); }

__global__ __launch_bounds__(256) void stage_ws_kernel(
    const float* __restrict__ pw1, const float* __restrict__ pb1,
    const float* __restrict__ pw2, const float* __restrict__ pb2,
    const float* __restrict__ mw1, const float* __restrict__ mb1,
    const float* __restrict__ mw2, const float* __restrict__ mb2,
    const float* __restrict__ sw1, const float* __restrict__ sb1,
    const float* __restrict__ sw2, const float* __restrict__ sb2,
    const float* __restrict__ gw1, const float* __restrict__ gb1,
    const float* __restrict__ gw2, const float* __restrict__ gb2,
    float* __restrict__ ws)
{
    const int t = threadIdx.x;
    auto cp = [&](const float* src, int off, int n) {
        for (int i = t; i < n; i += 256) ws[off + i] = src[i];
    };
    cp(pb1, OPB1, 5);   cp(pw1, OPW1, 50);
    cp(pb2, OPB2, 5);   cp(pw2, OPW2, 25);
    cp(mb1, OMB1, 15);  cp(mw1, OMW1, 345);
    cp(mb2, OMB2, 15);  cp(mw2, OMW2, 225);
    cp(sb1, OSB1, 5);   cp(sw1, OSW1, 115);
    cp(sb2, OSB2, 5);   cp(sw2, OSW2, 25);
    cp(gb1, OGB1, 5);   cp(gw1, OGW1, 25);
    cp(gw2, OGW2, 5);   cp(gb2, OGB2, 1);
}

__global__ __launch_bounds__(BLOCK, 4) void gmm_seq_kernel(
    const float* __restrict__ frames,
    const float* __restrict__ mu0,
    const float* __restrict__ Wt,     // contiguous weights in d_ws
    float* __restrict__ out)
{
    const int t2 = blockIdx.x * BLOCK + threadIdx.x;   // one thread = 2 adjacent px
    const int b   = t2 / HW2;
    const int rem = t2 - b * HW2;

    const float C0 = 0.06349363593424097f;      // (2*pi)^{-3/2}
    const float NH_L2E = -0.7213475204444817f;  // -0.5 * log2(e)

    // Per-pixel-pair carried state.
    v2f pi[Kk], mu[CKc], rinv[Kk];              // rinv = 1/sigma
#pragma unroll
    for (int k = 0; k < Kk; k++) { pi[k] = vsplat(0.2f); rinv[k] = vsplat(1.0f); }
    {
        const float* mp = mu0 + (size_t)b * CKc * HWc;
#pragma unroll
        for (int j = 0; j < CKc; j++)
            mu[j] = reinterpret_cast<const v2f*>(mp + (size_t)j * HWc)[rem];
    }

    const float* fbase = frames + ((size_t)b * Ss * Cc) * HWc;
    v2f x[Cc];
#pragma unroll
    for (int c = 0; c < Cc; c++)
        x[c] = reinterpret_cast<const v2f*>(fbase + (size_t)c * HWc)[rem];

#pragma unroll 1
    for (int s = 0; s < Ss; s++) {
        // Opaque per-iteration SCALAR offset: value is always 0 but unprovable.
        // Addresses stay wave-uniform (s_load path), loads stay loop-variant
        // (no cross-step hoisting of weight VALUES into registers).
        long woff = 0;
        asm volatile("" : "+s"(woff));
        const float* W = Wt + woff;

        // Prefetch next frame's pixels (clamped index -> branchless).
        const int sn = (s + 1 < Ss) ? s + 1 : s;
        v2f xn[Cc];
        {
            const float* fp = fbase + ((size_t)sn * Cc) * HWc;
#pragma unroll
            for (int c = 0; c < Cc; c++)
                xn[c] = reinterpret_cast<const v2f*>(fp + (size_t)c * HWc)[rem];
        }

        // ---- density(x; mu, 1/rinv) ----
        v2f alpha[Kk], rho[Kk];
#pragma unroll
        for (int k = 0; k < Kk; k++) {
            v2f inv_s2 = rinv[k] * rinv[k];
            v2f d0 = x[0] - mu[k * Cc + 0];
            v2f d1 = x[1] - mu[k * Cc + 1];
            v2f d2 = x[2] - mu[k * Cc + 2];
            v2f dist = vfma(d0, d0, vfma(d1, d1, d2 * d2));
            v2f coef = vsplat(C0) * inv_s2 * rinv[k];      // C0 * rinv^3
            v2f dens = coef * vexp2(vsplat(NH_L2E) * dist * inv_s2);
            alpha[k] = pi[k] * dens;
            rho[k] = alpha[k] * dens;
        }

        // ---- pi MLP (10 -> 5 -> 5) + softmax over K ----
        v2f piN[Kk];
        {
            v2f h[Kk];
#pragma unroll
            for (int j = 0; j < Kk; j++) {
                v2f a = vsplat(W[OPB1 + j]);
#pragma unroll
                for (int i = 0; i < Kk; i++) a = wfma(W[OPW1 + j * 2 * Kk + i], pi[i], a);
#pragma unroll
                for (int i = 0; i < Kk; i++) a = wfma(W[OPW1 + j * 2 * Kk + Kk + i], alpha[i], a);
                h[j] = vrelu(a);
            }
            v2f o[Kk];
            v2f m = vsplat(-1e30f);
#pragma unroll
            for (int j = 0; j < Kk; j++) {
                v2f a = vsplat(W[OPB2 + j]);
#pragma unroll
                for (int i = 0; i < Kk; i++) a = wfma(W[OPW2 + j * Kk + i], h[i], a);
                o[j] = a; m = vmax(m, a);
            }
            v2f sum = vsplat(0.0f);
#pragma unroll
            for (int j = 0; j < Kk; j++) { o[j] = vexp2(vsplat(LOG2E) * (o[j] - m)); sum = sum + o[j]; }
            v2f r = vrcp(sum);
#pragma unroll
            for (int j = 0; j < Kk; j++) piN[j] = o[j] * r;
        }

        // ---- mu MLP (23 -> 15 -> 15), sigmoid ----
        v2f muN[CKc];
        {
            v2f h[CKc];
#pragma unroll
            for (int j = 0; j < CKc; j++) {
                v2f a = vsplat(W[OMB1 + j]);
#pragma unroll
                for (int i = 0; i < Cc; i++)  a = wfma(W[OMW1 + j * 23 + i], x[i], a);
#pragma unroll
                for (int i = 0; i < CKc; i++) a = wfma(W[OMW1 + j * 23 + 3 + i], mu[i], a);
#pragma unroll
                for (int i = 0; i < Kk; i++)  a = wfma(W[OMW1 + j * 23 + 18 + i], rho[i], a);
                h[j] = vrelu(a);
            }
#pragma unroll
            for (int j = 0; j < CKc; j++) {
                v2f a = vsplat(W[OMB2 + j]);
#pragma unroll
                for (int i = 0; i < CKc; i++) a = wfma(W[OMW2 + j * CKc + i], h[i], a);
                muN[j] = vsigm(a);
            }
        }

        // ---- sigma MLP (23 -> 5 -> 5): rinvN = exp(-relu(a)) = 1/sigma_new ----
        v2f rinvN[Kk];
        {
            v2f h[Kk];
#pragma unroll
            for (int j = 0; j < Kk; j++) {
                v2f a = vsplat(W[OSB1 + j]);
#pragma unroll
                for (int i = 0; i < Cc; i++)  a = wfma(W[OSW1 + j * 23 + i], x[i], a);
#pragma unroll
                for (int i = 0; i < CKc; i++) a = wfma(W[OSW1 + j * 23 + 3 + i], muN[i], a);
#pragma unroll
                for (int i = 0; i < Kk; i++)  a = wfma(W[OSW1 + j * 23 + 18 + i], rho[i], a);
                h[j] = vrelu(a);
            }
#pragma unroll
            for (int j = 0; j < Kk; j++) {
                v2f a = vsplat(W[OSB2 + j]);
#pragma unroll
                for (int i = 0; i < Kk; i++) a = wfma(W[OSW2 + j * Kk + i], h[i], a);
                rinvN[j] = vexp2(vsplat(-LOG2E) * vrelu(a));
            }
        }

        // ---- dens2(x; muN, 1/rinvN), gamma MLP (5 -> 5 -> 1), sigmoid ----
        v2f gin[Kk];
#pragma unroll
        for (int k = 0; k < Kk; k++) {
            v2f inv_s2 = rinvN[k] * rinvN[k];
            v2f d0 = x[0] - muN[k * Cc + 0];
            v2f d1 = x[1] - muN[k * Cc + 1];
            v2f d2 = x[2] - muN[k * Cc + 2];
            v2f dist = vfma(d0, d0, vfma(d1, d1, d2 * d2));
            v2f coef = vsplat(C0) * inv_s2 * rinvN[k];
            gin[k] = piN[k] * (coef * vexp2(vsplat(NH_L2E) * dist * inv_s2));
        }
        {
            v2f h[Kk];
#pragma unroll
            for (int j = 0; j < Kk; j++) {
                v2f a = vsplat(W[OGB1 + j]);
#pragma unroll
                for (int i = 0; i < Kk; i++) a = wfma(W[OGW1 + j * Kk + i], gin[i], a);
                h[j] = vrelu(a);
            }
            v2f go = vsplat(W[OGB2]);
#pragma unroll
            for (int i = 0; i < Kk; i++) go = wfma(W[OGW2 + i], h[i], go);
            reinterpret_cast<v2f*>(out + (size_t)(b * Ss + s) * HWc)[rem] = vsigm(go);
        }

        // ---- carry state ----
#pragma unroll
        for (int k = 0; k < Kk; k++) { pi[k] = piN[k]; rinv[k] = rinvN[k]; }
#pragma unroll
        for (int j = 0; j < CKc; j++) mu[j] = muN[j];
#pragma unroll
        for (int c = 0; c < Cc; c++) x[c] = xn[c];
    }
}

} // namespace

extern "C" void kernel_launch(void* const* d_in, const int* in_sizes, int n_in,
                              void* d_out, int out_size, void* d_ws, size_t ws_size,
                              hipStream_t stream) {
    const float* frames = (const float*)d_in[0];
    const float* mu0    = (const float*)d_in[2];
    const float* pw1 = (const float*)d_in[3];
    const float* pb1 = (const float*)d_in[4];
    const float* pw2 = (const float*)d_in[5];
    const float* pb2 = (const float*)d_in[6];
    const float* mw1 = (const float*)d_in[7];
    const float* mb1 = (const float*)d_in[8];
    const float* mw2 = (const float*)d_in[9];
    const float* mb2 = (const float*)d_in[10];
    const float* sw1 = (const float*)d_in[11];
    const float* sb1 = (const float*)d_in[12];
    const float* sw2 = (const float*)d_in[13];
    const float* sb2 = (const float*)d_in[14];
    const float* gw1 = (const float*)d_in[15];
    const float* gb1 = (const float*)d_in[16];
    const float* gw2 = (const float*)d_in[17];
    const float* gb2 = (const float*)d_in[18];
    float* out = (float*)d_out;
    float* ws  = (float*)d_ws;

    // Stage all weights contiguous in d_ws (consumption order).
    stage_ws_kernel<<<1, 256, 0, stream>>>(
        pw1, pb1, pw2, pb2, mw1, mb1, mw2, mb2,
        sw1, sb1, sw2, sb2, gw1, gb1, gw2, gb2, ws);

    const int total2 = Bb * HW2;                     // 294,912 pixel-pairs
    const int grid = (total2 + BLOCK - 1) / BLOCK;   // 2304 blocks of 128

    gmm_seq_kernel<<<grid, BLOCK, 0, stream>>>(frames, mu0, ws, out);
}